// Round 7
// baseline (147.493 us; speedup 1.0000x reference)
//
#include <hip/hip_runtime.h>

#define THREADS 256
#define NQUAD 524288             // 2097152 rows / 4 rows per thread
#define BLOCKS (NQUAD / THREADS) // 2048
#define DT 0.005f
#define INV_HUBER 200.0f         // 1/0.005

#define NELEM 6291456.0          // 128*16384*3
#define CNT16 391296.0           // 128*1019*3
#define CNT32 194688.0           // 128*507*3

__device__ __forceinline__ float rcpf(float x) {
    return __builtin_amdgcn_rcpf(x);      // ~1e-7 rel, plenty here
}

// acos via A&S 4.4.46 7-term poly: |err| < 2e-8 rad (exact at f32)
__device__ __forceinline__ float acos_poly(float x) {
    float ax = fabsf(x);
    float p = fmaf(ax, -0.0012624911f, 0.0066700901f);
    p = fmaf(ax, p, -0.0170881256f);
    p = fmaf(ax, p, 0.0308918810f);
    p = fmaf(ax, p, -0.0501743046f);
    p = fmaf(ax, p, 0.0889789874f);
    p = fmaf(ax, p, -0.2145988016f);
    p = fmaf(ax, p, 1.5707963050f);
    float r = sqrtf(fmaxf(1.0f - ax, 0.0f)) * p;
    return x < 0.0f ? 3.14159265358979f - r : r;
}

// Rodrigues, small-angle (|phi| <= ~0.04): Taylor st/ct, error ~4e-13 rel
__device__ __forceinline__ void so3_exp_small(float x, float y, float z, float R[9]) {
    float a2 = x * x + y * y + z * z;
    float st = 1.0f - a2 * (1.0f / 6.0f) * (1.0f - a2 * (1.0f / 20.0f));
    float ct = 0.5f - a2 * (1.0f / 24.0f) * (1.0f - a2 * (1.0f / 30.0f));
    R[0] = 1.0f + ct * (x * x - a2);
    R[1] = ct * (x * y) - st * z;
    R[2] = ct * (x * z) + st * y;
    R[3] = ct * (x * y) + st * z;
    R[4] = 1.0f + ct * (y * y - a2);
    R[5] = ct * (y * z) - st * x;
    R[6] = ct * (x * z) - st * y;
    R[7] = ct * (y * z) + st * x;
    R[8] = 1.0f + ct * (z * z - a2);
}

// Rodrigues, full range (dw16 angles up to ~6 rad) — hardware trig
__device__ __forceinline__ void so3_exp_full(float x, float y, float z, float R[9]) {
    float a2 = x * x + y * y + z * z;
    bool sm = a2 < 1e-12f;
    float a2s = sm ? 1.0f : a2;
    float a = sqrtf(a2s);
    float s = __sinf(a);
    float c = __cosf(a);
    float st = sm ? (1.0f - a2 * (1.0f / 6.0f)) : (s * rcpf(a));
    float ct = sm ? (0.5f - a2 * (1.0f / 24.0f)) : ((1.0f - c) * rcpf(a2s));
    R[0] = 1.0f + ct * (x * x - a2);
    R[1] = ct * (x * y) - st * z;
    R[2] = ct * (x * z) + st * y;
    R[3] = ct * (x * y) + st * z;
    R[4] = 1.0f + ct * (y * y - a2);
    R[5] = ct * (y * z) - st * x;
    R[6] = ct * (x * z) - st * y;
    R[7] = ct * (y * z) + st * x;
    R[8] = 1.0f + ct * (z * z - a2);
}

__device__ __forceinline__ void mm3(const float A[9], const float B[9], float C[9]) {
#pragma unroll
    for (int i = 0; i < 3; ++i) {
        float a0 = A[3 * i], a1 = A[3 * i + 1], a2 = A[3 * i + 2];
        C[3 * i + 0] = a0 * B[0] + a1 * B[3] + a2 * B[6];
        C[3 * i + 1] = a0 * B[1] + a1 * B[4] + a2 * B[7];
        C[3 * i + 2] = a0 * B[2] + a1 * B[5] + a2 * B[8];
    }
}

// sum of huber( so3_log(A^T B) / HUBER ) over the 3 components
__device__ __forceinline__ float huber_bmtm(const float A[9], const float B[9]) {
    float tr = 0.f, w0 = 0.f, w1 = 0.f, w2 = 0.f;
#pragma unroll
    for (int k = 0; k < 3; ++k) {
        float a0 = A[3 * k], a1 = A[3 * k + 1], a2v = A[3 * k + 2];
        float b0 = B[3 * k], b1 = B[3 * k + 1], b2v = B[3 * k + 2];
        tr += a0 * b0 + a1 * b1 + a2v * b2v;
        w0 += a2v * b1 - a1 * b2v;
        w1 += a0 * b2v - a2v * b0;
        w2 += a1 * b0 - a0 * b1;
    }
    float cs = 0.5f * (tr - 1.0f);
    cs = fminf(fmaxf(cs, -1.0f + 1e-6f), 1.0f - 1e-6f);
    float ang = acos_poly(cs);
    float sn = sqrtf(fmaxf(1.0f - cs * cs, 0.0f));   // sin(acos(cs)) >= ~1.4e-3
    float fac = ang * 0.5f * rcpf(sn);
    float h = 0.0f, r;
    r = fabsf(fac * w0 * INV_HUBER); h += (r < 1.0f) ? 0.5f * r * r : (r - 0.5f);
    r = fabsf(fac * w1 * INV_HUBER); h += (r < 1.0f) ? 0.5f * r * r : (r - 0.5f);
    r = fabsf(fac * w2 * INV_HUBER); h += (r < 1.0f) ? 0.5f * r * r : (r - 0.5f);
    return h;
}

// gaussian NLL partial for 4 elements
__device__ __forceinline__ float gnll4(float4 h, float4 g, float4 m, float4 s) {
    float p = 0.f;
#pragma unroll
    for (int k = 0; k < 4; ++k) {
        float hv = (&h.x)[k], gv = (&g.x)[k], mv = (&m.x)[k], sv = (&s.x)[k];
        float v = fmaxf(sv * sv, 1e-6f);
        float d = gv - hv - mv;
        float rv = rcpf(v);
        rv = rv * (2.0f - v * rv);                   // 1 NR step
        p += __logf(v) + d * d * rv;
    }
    return p;
}

__global__ __launch_bounds__(THREADS) void dg_loss_kernel(
    const float* __restrict__ w_hat, const float* __restrict__ dw16,
    const float* __restrict__ w_gt, const float* __restrict__ w_mean,
    const float* __restrict__ w_std, double* __restrict__ partial)
{
    const int tid = threadIdx.x;
    const int t = blockIdx.x * THREADS + tid;           // quad-row index
    const int lane = tid & 63;

    __shared__ float4 swh[768];                         // block's w_hat chunk, 12 KB

    // ---- fully-coalesced loads: 3 contiguous float4 per array per thread ----
    const size_t base = (size_t)blockIdx.x * 768;
    const float4* h4 = (const float4*)w_hat;
    const float4* g4 = (const float4*)w_gt;
    const float4* m4 = (const float4*)w_mean;
    const float4* s4 = (const float4*)w_std;
    float4 H[3], G[3], M[3], S[3];
#pragma unroll
    for (int k = 0; k < 3; ++k) {
        H[k] = h4[base + k * 256 + tid];
        G[k] = g4[base + k * 256 + tid];
        M[k] = m4[base + k * 256 + tid];
        S[k] = s4[base + k * 256 + tid];
    }
    // dw16 row 16*b for this 4-lane group (broadcast, tiny array)
    const int b = t >> 2;                               // global 16-block index
    float4 q4 = ((const float4*)dw16)[(size_t)b * 12];

    // stage w_hat chunk to LDS (unit-stride write, conflict-free)
#pragma unroll
    for (int k = 0; k < 3; ++k)
        swh[k * 256 + tid] = H[k];
    __syncthreads();

    // ---- gaussian NLL on this thread's 12 contiguous elements ----
    double lg = 0.5 * (double)(gnll4(H[0], G[0], M[0], S[0]) +
                               gnll4(H[1], G[1], M[1], S[1]) +
                               gnll4(H[2], G[2], M[2], S[2]));

    // ---- fetch own 4 rows from LDS (48B stride, <=2-way bank alias: free) ----
    float4 r0 = swh[tid * 3 + 0];
    float4 r1 = swh[tid * 3 + 1];
    float4 r2 = swh[tid * 3 + 2];

    // ---- in-lane: 4 exps + balanced 3-mm3 tree (reference association) ----
    float E0[9], E1[9], E2[9], E3[9], T01[9], T23[9], P[9];
    so3_exp_small(DT * r0.x, DT * r0.y, DT * r0.z, E0);
    so3_exp_small(DT * r0.w, DT * r1.x, DT * r1.y, E1);
    so3_exp_small(DT * r1.z, DT * r1.w, DT * r2.x, E2);
    so3_exp_small(DT * r2.y, DT * r2.z, DT * r2.w, E3);
    mm3(E0, E1, T01);
    mm3(E2, E3, T23);
    mm3(T01, T23, P);                                   // product of my 4 rows

    // ---- butterfly over 4-lane groups: strides 1,2 -> ordered 16-row product ----
#pragma unroll
    for (int s = 1; s <= 2; s <<= 1) {
        float Nb[9];
#pragma unroll
        for (int e = 0; e < 9; ++e) Nb[e] = __shfl_xor(P[e], s);
        const bool rt = (lane & s) != 0;
        float A[9], B[9], T[9];
#pragma unroll
        for (int e = 0; e < 9; ++e) { A[e] = rt ? Nb[e] : P[e]; B[e] = rt ? P[e] : Nb[e]; }
        mm3(A, B, T);
#pragma unroll
        for (int e = 0; e < 9; ++e) P[e] = T[e];
    }

    // Q16 = exp(dw16 row) — every lane (branch-free, hardware trig)
    float Q[9];
    so3_exp_full(q4.x, q4.y, q4.z, Q);

    // ---- merged 16/32-level huber: ONE wave-wide huber call ----
    float Pn[9], Qn[9];
#pragma unroll
    for (int e = 0; e < 9; ++e) {
        Pn[e] = __shfl_xor(P[e], 4);                    // partner 16-group
        Qn[e] = __shfl_xor(Q[e], 4);
    }
    float T1[9], T2[9];
    mm3(P, Pn, T1);                                     // valid (even*odd) on even-group lanes
    mm3(Q, Qn, T2);
    const bool role16 = (lane & 3) == 0;                // 16 lanes: one per 16-block
    const bool role32 = (lane & 7) == 1;                // 8 lanes: one per 32-block (even group)
    float A[9], B[9];
#pragma unroll
    for (int e = 0; e < 9; ++e) {
        A[e] = role16 ? P[e] : T1[e];
        B[e] = role16 ? Q[e] : T2[e];
    }
    float hub = huber_bmtm(A, B);
    double lh16 = 0.0, lh32 = 0.0;
    if (role16 && ((b & 1023) >= 5)) lh16 = (double)hub;    // skip N0=5 16-blocks/traj
    const int c = t >> 3;                                   // global 32-block index
    if (role32 && ((c & 511) >= 5)) lh32 = (double)hub;     // skip N0=5 32-blocks/traj

    // ---- block reduction: pre-scaled single double, plain store (no atomics) ----
    double part = lg * (1.0 / NELEM) + lh16 * (25.0 / CNT16) + lh32 * (6.25 / CNT32);
    __shared__ double s_p[4];
#pragma unroll
    for (int off = 32; off > 0; off >>= 1)
        part += __shfl_down(part, off);
    const int wv = tid >> 6;
    if (lane == 0) s_p[wv] = part;
    __syncthreads();
    if (tid == 0)
        partial[blockIdx.x] = s_p[0] + s_p[1] + s_p[2] + s_p[3];
}

__global__ __launch_bounds__(THREADS) void finalize_kernel(
    const double* __restrict__ partial, float* __restrict__ out)
{
    double s = 0.0;
#pragma unroll
    for (int i = 0; i < BLOCKS / THREADS; ++i)          // 8 strided loads each
        s += partial[i * THREADS + threadIdx.x];
    __shared__ double s_p[4];
#pragma unroll
    for (int off = 32; off > 0; off >>= 1)
        s += __shfl_down(s, off);
    const int lane = threadIdx.x & 63, wv = threadIdx.x >> 6;
    if (lane == 0) s_p[wv] = s;
    __syncthreads();
    if (threadIdx.x == 0)
        out[0] = (float)(s_p[0] + s_p[1] + s_p[2] + s_p[3]);
}

extern "C" void kernel_launch(void* const* d_in, const int* in_sizes, int n_in,
                              void* d_out, int out_size, void* d_ws, size_t ws_size,
                              hipStream_t stream) {
    const float* w_hat = (const float*)d_in[0];
    const float* dw16 = (const float*)d_in[1];
    const float* w_gt = (const float*)d_in[2];
    const float* w_mean = (const float*)d_in[3];
    const float* w_std = (const float*)d_in[4];
    float* out = (float*)d_out;
    double* partial = (double*)d_ws;                   // BLOCKS doubles = 16 KB

    dg_loss_kernel<<<BLOCKS, THREADS, 0, stream>>>(
        w_hat, dw16, w_gt, w_mean, w_std, partial);
    finalize_kernel<<<1, THREADS, 0, stream>>>(partial, out);
}